// Round 9
// baseline (107.796 us; speedup 1.0000x reference)
//
#include <hip/hip_runtime.h>

// LatticeGaussian: out = W @ U - U, W[i,j] = exp(-0.5*||ref_i - ref_j||^2)
// N=8192, C=16, D=5, fp32. Exact pairwise evaluation, O(N^2).
//
// R9 == R8 == R7 (three GPU timeouts; MI=4 experiment still pending).
// R7 vs R6 (lg_main 51us, VALUBusy 53%): kernel is LDS-PIPE-bound, not
// latency-bound. Per jj a wave issues 6 broadcast DS reads (~45cy of the
// CU-shared LDS pipe) vs only ~23cy VALU demand -> 2:1 oversubscription
// (measured VALUBusy 53% matches). Fix: MI 2 -> 4 i-rows/thread: DS per
// jj unchanged, VALU doubles -> LDS:VALU ~ 1:1.
//  - Geometry: TPB=256, IPB=1024, NIB=8, NSEG=64, grid=512 (2 blocks/CU,
//    8 waves/CU; short DS latency + 4 indep exp chains = enough ILP).
//  - part layout [seg][cq][i] (float4): main stores AND reduce loads
//    fully coalesced.
// Prediction: lg_main ~29us, VALUBusy ~82%, total ~83us.

#define N_ROWS 8192
#define C_CH   16
#define D_DIM  5
#define TPB    256
#define MI     4
#define IPB    (TPB * MI)        // 1024 i per block
#define NIB    (N_ROWS / IPB)    // 8 i-chunks
#define NSEG   64
#define JPB    (N_ROWS / NSEG)   // 128 j per segment

#if __has_builtin(__builtin_amdgcn_exp2f)
#define EXP2(x) __builtin_amdgcn_exp2f(x)
#else
#define EXP2(x) exp2f(x)
#endif

#define LOG2E 1.4426950408889634f

__global__ __launch_bounds__(TPB) void lg_main(const float* __restrict__ U,
                                               const float* __restrict__ ref,
                                               float* __restrict__ part) {
    __shared__ float sj[JPB][8];    // [0..4]=log2e*ref, [5]=-0.5*log2e*|r|^2
    __shared__ float su[JPB][16];   // U rows

    const int bid = blockIdx.x;
    const int ib  = bid % NIB;
    const int seg = bid / NIB;
    const int tid = threadIdx.x;
    const int j0  = seg * JPB;

    // ---- Per-thread i-rows: issue global loads early (overlap staging) ----
    const int ibase = ib * IPB + tid;
    float r[MI][D_DIM];
#pragma unroll
    for (int q = 0; q < MI; ++q) {
        const int i = ibase + q * TPB;
#pragma unroll
        for (int d = 0; d < D_DIM; ++d) r[q][d] = ref[i * D_DIM + d];
    }

    // ---- Stage j-segment into LDS (compute pack from ref in-place) ----
    if (tid < JPB) {
        const int j = j0 + tid;
        const float v0 = ref[j * D_DIM + 0];
        const float v1 = ref[j * D_DIM + 1];
        const float v2 = ref[j * D_DIM + 2];
        const float v3 = ref[j * D_DIM + 3];
        const float v4 = ref[j * D_DIM + 4];
        float s = v0 * v0;
        s = fmaf(v1, v1, s); s = fmaf(v2, v2, s);
        s = fmaf(v3, v3, s); s = fmaf(v4, v4, s);
        sj[tid][0] = v0 * LOG2E; sj[tid][1] = v1 * LOG2E;
        sj[tid][2] = v2 * LOG2E; sj[tid][3] = v3 * LOG2E;
        sj[tid][4] = v4 * LOG2E; sj[tid][5] = -0.5f * LOG2E * s;
        sj[tid][6] = 0.0f;       sj[tid][7] = 0.0f;
    }
    {
        const float4* __restrict__ U4 = reinterpret_cast<const float4*>(U);
        float4* su4 = reinterpret_cast<float4*>(&su[0][0]);
#pragma unroll
        for (int k = 0; k < (JPB * 4) / TPB; ++k) {
            const int idx = k * TPB + tid;
            su4[idx] = U4[(size_t)j0 * 4 + idx];
        }
    }
    __syncthreads();

    float a[MI];
#pragma unroll
    for (int q = 0; q < MI; ++q) {
        float s = r[q][0] * r[q][0];
        s = fmaf(r[q][1], r[q][1], s); s = fmaf(r[q][2], r[q][2], s);
        s = fmaf(r[q][3], r[q][3], s); s = fmaf(r[q][4], r[q][4], s);
        a[q] = -0.5f * LOG2E * s;
    }

    float acc[MI][C_CH];
#pragma unroll
    for (int q = 0; q < MI; ++q)
#pragma unroll
        for (int c = 0; c < C_CH; ++c) acc[q][c] = 0.0f;

#pragma unroll 4
    for (int jj = 0; jj < JPB; ++jj) {
        const float4 sA = *reinterpret_cast<const float4*>(&sj[jj][0]);
        const float2 sB = *reinterpret_cast<const float2*>(&sj[jj][4]);

        float w[MI];
#pragma unroll
        for (int q = 0; q < MI; ++q) {
            float e = a[q] + sB.y;
            e = fmaf(r[q][0], sA.x, e);
            e = fmaf(r[q][1], sA.y, e);
            e = fmaf(r[q][2], sA.z, e);
            e = fmaf(r[q][3], sA.w, e);
            e = fmaf(r[q][4], sB.x, e);
            w[q] = EXP2(e);
        }

        const float4 u0 = *reinterpret_cast<const float4*>(&su[jj][0]);
        const float4 u1 = *reinterpret_cast<const float4*>(&su[jj][4]);
        const float4 u2 = *reinterpret_cast<const float4*>(&su[jj][8]);
        const float4 u3 = *reinterpret_cast<const float4*>(&su[jj][12]);

#pragma unroll
        for (int q = 0; q < MI; ++q) {
            acc[q][0]  = fmaf(w[q], u0.x, acc[q][0]);
            acc[q][1]  = fmaf(w[q], u0.y, acc[q][1]);
            acc[q][2]  = fmaf(w[q], u0.z, acc[q][2]);
            acc[q][3]  = fmaf(w[q], u0.w, acc[q][3]);
            acc[q][4]  = fmaf(w[q], u1.x, acc[q][4]);
            acc[q][5]  = fmaf(w[q], u1.y, acc[q][5]);
            acc[q][6]  = fmaf(w[q], u1.z, acc[q][6]);
            acc[q][7]  = fmaf(w[q], u1.w, acc[q][7]);
            acc[q][8]  = fmaf(w[q], u2.x, acc[q][8]);
            acc[q][9]  = fmaf(w[q], u2.y, acc[q][9]);
            acc[q][10] = fmaf(w[q], u2.z, acc[q][10]);
            acc[q][11] = fmaf(w[q], u2.w, acc[q][11]);
            acc[q][12] = fmaf(w[q], u3.x, acc[q][12]);
            acc[q][13] = fmaf(w[q], u3.y, acc[q][13]);
            acc[q][14] = fmaf(w[q], u3.z, acc[q][14]);
            acc[q][15] = fmaf(w[q], u3.w, acc[q][15]);
        }
    }

    // part layout: [seg][cq][i] as float4 -> coalesced stores (lanes = i).
    float4* part4 = reinterpret_cast<float4*>(part);
#pragma unroll
    for (int q = 0; q < MI; ++q) {
        const int i = ibase + q * TPB;
#pragma unroll
        for (int cq = 0; cq < 4; ++cq) {
            part4[((size_t)seg * 4 + cq) * N_ROWS + i] =
                make_float4(acc[q][cq * 4 + 0], acc[q][cq * 4 + 1],
                            acc[q][cq * 4 + 2], acc[q][cq * 4 + 3]);
        }
    }
}

__global__ __launch_bounds__(TPB) void lg_reduce(const float* __restrict__ U,
                                                 const float* __restrict__ part,
                                                 float* __restrict__ out) {
    const int t  = blockIdx.x * TPB + threadIdx.x;  // [0, 32768)
    const int i  = t & (N_ROWS - 1);
    const int cq = t >> 13;                         // N_ROWS = 2^13
    const float4 u = reinterpret_cast<const float4*>(U)[i * 4 + cq];
    float4 s = make_float4(-u.x, -u.y, -u.z, -u.w);
    const float4* p = reinterpret_cast<const float4*>(part);
#pragma unroll 8
    for (int seg = 0; seg < NSEG; ++seg) {
        const float4 v = p[((size_t)seg * 4 + cq) * N_ROWS + i];
        s.x += v.x; s.y += v.y; s.z += v.z; s.w += v.w;
    }
    reinterpret_cast<float4*>(out)[i * 4 + cq] = s;
}

// ---- Last-resort fallback (ws too small): init -U + atomics ----

__global__ __launch_bounds__(TPB) void lg_init(const float* __restrict__ U,
                                               float* __restrict__ out) {
    const int idx = blockIdx.x * TPB + threadIdx.x;
    if (idx < N_ROWS * C_CH) out[idx] = -U[idx];
}

__global__ __launch_bounds__(TPB) void lg_main_atomic(const float* __restrict__ U,
                                                      const float* __restrict__ ref,
                                                      float* __restrict__ out) {
    constexpr int NS  = 32;
    constexpr int JP  = N_ROWS / NS;
    constexpr int NI  = N_ROWS / TPB;
    const int bid = blockIdx.x;
    const int ib  = bid % NI;
    const int sg  = bid / NI;
    const int i   = ib * TPB + threadIdx.x;

    const float r0 = ref[i * D_DIM + 0];
    const float r1 = ref[i * D_DIM + 1];
    const float r2 = ref[i * D_DIM + 2];
    const float r3 = ref[i * D_DIM + 3];
    const float r4 = ref[i * D_DIM + 4];

    float acc[C_CH];
#pragma unroll
    for (int c = 0; c < C_CH; ++c) acc[c] = 0.0f;

    const float4* __restrict__ U4 = reinterpret_cast<const float4*>(U);
    const int j0 = sg * JP;
#pragma unroll 4
    for (int j = j0; j < j0 + JP; ++j) {
        const float d0 = r0 - ref[j * D_DIM + 0];
        const float d1 = r1 - ref[j * D_DIM + 1];
        const float d2 = r2 - ref[j * D_DIM + 2];
        const float d3 = r3 - ref[j * D_DIM + 3];
        const float d4 = r4 - ref[j * D_DIM + 4];
        float dsq = d0 * d0;
        dsq = fmaf(d1, d1, dsq); dsq = fmaf(d2, d2, dsq);
        dsq = fmaf(d3, d3, dsq); dsq = fmaf(d4, d4, dsq);
        const float w = __expf(-0.5f * dsq);

        const float4 u0 = U4[j * 4 + 0];
        const float4 u1 = U4[j * 4 + 1];
        const float4 u2 = U4[j * 4 + 2];
        const float4 u3 = U4[j * 4 + 3];
        acc[0]  = fmaf(w, u0.x, acc[0]);   acc[1]  = fmaf(w, u0.y, acc[1]);
        acc[2]  = fmaf(w, u0.z, acc[2]);   acc[3]  = fmaf(w, u0.w, acc[3]);
        acc[4]  = fmaf(w, u1.x, acc[4]);   acc[5]  = fmaf(w, u1.y, acc[5]);
        acc[6]  = fmaf(w, u1.z, acc[6]);   acc[7]  = fmaf(w, u1.w, acc[7]);
        acc[8]  = fmaf(w, u2.x, acc[8]);   acc[9]  = fmaf(w, u2.y, acc[9]);
        acc[10] = fmaf(w, u2.z, acc[10]);  acc[11] = fmaf(w, u2.w, acc[11]);
        acc[12] = fmaf(w, u3.x, acc[12]);  acc[13] = fmaf(w, u3.y, acc[13]);
        acc[14] = fmaf(w, u3.z, acc[14]);  acc[15] = fmaf(w, u3.w, acc[15]);
    }

    float* o = out + (size_t)i * C_CH;
#pragma unroll
    for (int c = 0; c < C_CH; ++c) atomicAdd(&o[c], acc[c]);
}

extern "C" void kernel_launch(void* const* d_in, const int* in_sizes, int n_in,
                              void* d_out, int out_size, void* d_ws, size_t ws_size,
                              hipStream_t stream) {
    const float* U   = (const float*)d_in[0];   // [8192,16]
    const float* ref = (const float*)d_in[1];   // [8192,5]
    float* out       = (float*)d_out;           // [8192,16]

    const size_t need = (size_t)NSEG * N_ROWS * C_CH * sizeof(float);  // 33.6MB

    if (ws_size >= need) {
        float* part = (float*)d_ws;
        hipLaunchKernelGGL(lg_main, dim3(NIB * NSEG), dim3(TPB), 0, stream,
                           U, ref, part);
        hipLaunchKernelGGL(lg_reduce, dim3(N_ROWS * C_CH / 4 / TPB), dim3(TPB),
                           0, stream, U, part, out);
    } else {
        hipLaunchKernelGGL(lg_init, dim3((N_ROWS * C_CH + TPB - 1) / TPB), dim3(TPB),
                           0, stream, U, out);
        hipLaunchKernelGGL(lg_main_atomic, dim3((N_ROWS / TPB) * 32), dim3(TPB),
                           0, stream, U, ref, out);
    }
}

// Round 10
// 106.925 us; speedup vs baseline: 1.0081x; 1.0081x over previous
//
#include <hip/hip_runtime.h>

// LatticeGaussian: out = W @ U - U, W[i,j] = exp(-0.5*||ref_i - ref_j||^2)
// N=8192, C=16, D=5, fp32. Exact pairwise evaluation, O(N^2).
//
// R10 vs R9: MI=4 FAILED (57us, VALUBusy 48%, worse than R6's MI=2 51us).
// Cross-round invariant: VALU-busy time == 27us in R2/R3/R6/R9 regardless
// of occupancy (12-41%) or DS:VALU ratio -> neither TLP nor pipe balance
// is the limiter. Revised theory: per-iteration lgkm LATENCY exposure --
// compiler issues each jj's 6 ds_reads right before use (92cy compute +
// ~82cy exposed wait = 174cy/jj -> 53% busy, matches R6).
// Fix: back to R6 geometry (MI=2, NSEG=64, 1024 blocks, 4 waves/SIMD) +
// EXPLICIT 2-stage register prefetch of jj+1 LDS data (named reg sets,
// +1 pad row for branchless tail). Wait now lands after 92cy of compute.
// Prediction: lg_main ~32us, VALUBusy ~80%, total ~80-85us.

#define N_ROWS 8192
#define C_CH   16
#define D_DIM  5
#define TPB    256
#define MI     2
#define IPB    (TPB * MI)        // 512 i per block
#define NIB    (N_ROWS / IPB)    // 16 i-chunks
#define NSEG   64
#define JPB    (N_ROWS / NSEG)   // 128 j per segment

#if __has_builtin(__builtin_amdgcn_exp2f)
#define EXP2(x) __builtin_amdgcn_exp2f(x)
#else
#define EXP2(x) exp2f(x)
#endif

#define LOG2E 1.4426950408889634f

__global__ __launch_bounds__(TPB) void lg_main(const float* __restrict__ U,
                                               const float* __restrict__ ref,
                                               float* __restrict__ part) {
    // +1 pad row: tail prefetch reads row JPB unconditionally (never used).
    __shared__ float sj[JPB + 1][8];   // [0..4]=log2e*ref, [5]=-0.5*log2e*|r|^2
    __shared__ float su[JPB + 1][16];  // U rows

    const int bid = blockIdx.x;
    const int ib  = bid % NIB;
    const int seg = bid / NIB;
    const int tid = threadIdx.x;
    const int j0  = seg * JPB;

    // ---- Per-thread i-rows: issue global loads early (overlap staging) ----
    const int i0 = ib * IPB + tid;
    const int i1 = i0 + TPB;
    const float r00 = ref[i0 * D_DIM + 0], r10 = ref[i1 * D_DIM + 0];
    const float r01 = ref[i0 * D_DIM + 1], r11 = ref[i1 * D_DIM + 1];
    const float r02 = ref[i0 * D_DIM + 2], r12 = ref[i1 * D_DIM + 2];
    const float r03 = ref[i0 * D_DIM + 3], r13 = ref[i1 * D_DIM + 3];
    const float r04 = ref[i0 * D_DIM + 4], r14 = ref[i1 * D_DIM + 4];

    // ---- Stage j-segment into LDS (compute pack from ref in-place) ----
    if (tid < JPB) {
        const int j = j0 + tid;
        const float v0 = ref[j * D_DIM + 0];
        const float v1 = ref[j * D_DIM + 1];
        const float v2 = ref[j * D_DIM + 2];
        const float v3 = ref[j * D_DIM + 3];
        const float v4 = ref[j * D_DIM + 4];
        float s = v0 * v0;
        s = fmaf(v1, v1, s); s = fmaf(v2, v2, s);
        s = fmaf(v3, v3, s); s = fmaf(v4, v4, s);
        sj[tid][0] = v0 * LOG2E; sj[tid][1] = v1 * LOG2E;
        sj[tid][2] = v2 * LOG2E; sj[tid][3] = v3 * LOG2E;
        sj[tid][4] = v4 * LOG2E; sj[tid][5] = -0.5f * LOG2E * s;
        sj[tid][6] = 0.0f;       sj[tid][7] = 0.0f;
    }
    {
        const float4* __restrict__ U4 = reinterpret_cast<const float4*>(U);
        float4* su4 = reinterpret_cast<float4*>(&su[0][0]);
#pragma unroll
        for (int k = 0; k < (JPB * 4) / TPB; ++k) {
            const int idx = k * TPB + tid;
            // su rows are [16] wide; pad row not written (never read as data)
            su4[(idx / 4) * 4 + (idx & 3)] = U4[(size_t)j0 * 4 + idx];
        }
    }
    __syncthreads();

    float a0 = r00 * r00, a1 = r10 * r10;
    a0 = fmaf(r01, r01, a0); a1 = fmaf(r11, r11, a1);
    a0 = fmaf(r02, r02, a0); a1 = fmaf(r12, r12, a1);
    a0 = fmaf(r03, r03, a0); a1 = fmaf(r13, r13, a1);
    a0 = fmaf(r04, r04, a0); a1 = fmaf(r14, r14, a1);
    a0 *= -0.5f * LOG2E;     a1 *= -0.5f * LOG2E;

    float acc0[C_CH], acc1[C_CH];
#pragma unroll
    for (int c = 0; c < C_CH; ++c) { acc0[c] = 0.0f; acc1[c] = 0.0f; }

#define LG_COMPUTE(sA, sB, u0, u1, u2, u3)                                   \
    {                                                                        \
        float e0 = a0 + sB.y;                                                \
        float e1 = a1 + sB.y;                                                \
        e0 = fmaf(r00, sA.x, e0);  e1 = fmaf(r10, sA.x, e1);                 \
        e0 = fmaf(r01, sA.y, e0);  e1 = fmaf(r11, sA.y, e1);                 \
        e0 = fmaf(r02, sA.z, e0);  e1 = fmaf(r12, sA.z, e1);                 \
        e0 = fmaf(r03, sA.w, e0);  e1 = fmaf(r13, sA.w, e1);                 \
        e0 = fmaf(r04, sB.x, e0);  e1 = fmaf(r14, sB.x, e1);                 \
        const float w0 = EXP2(e0);                                           \
        const float w1 = EXP2(e1);                                           \
        acc0[0]  = fmaf(w0, u0.x, acc0[0]);  acc1[0]  = fmaf(w1, u0.x, acc1[0]); \
        acc0[1]  = fmaf(w0, u0.y, acc0[1]);  acc1[1]  = fmaf(w1, u0.y, acc1[1]); \
        acc0[2]  = fmaf(w0, u0.z, acc0[2]);  acc1[2]  = fmaf(w1, u0.z, acc1[2]); \
        acc0[3]  = fmaf(w0, u0.w, acc0[3]);  acc1[3]  = fmaf(w1, u0.w, acc1[3]); \
        acc0[4]  = fmaf(w0, u1.x, acc0[4]);  acc1[4]  = fmaf(w1, u1.x, acc1[4]); \
        acc0[5]  = fmaf(w0, u1.y, acc0[5]);  acc1[5]  = fmaf(w1, u1.y, acc1[5]); \
        acc0[6]  = fmaf(w0, u1.z, acc0[6]);  acc1[6]  = fmaf(w1, u1.z, acc1[6]); \
        acc0[7]  = fmaf(w0, u1.w, acc0[7]);  acc1[7]  = fmaf(w1, u1.w, acc1[7]); \
        acc0[8]  = fmaf(w0, u2.x, acc0[8]);  acc1[8]  = fmaf(w1, u2.x, acc1[8]); \
        acc0[9]  = fmaf(w0, u2.y, acc0[9]);  acc1[9]  = fmaf(w1, u2.y, acc1[9]); \
        acc0[10] = fmaf(w0, u2.z, acc0[10]); acc1[10] = fmaf(w1, u2.z, acc1[10]); \
        acc0[11] = fmaf(w0, u2.w, acc0[11]); acc1[11] = fmaf(w1, u2.w, acc1[11]); \
        acc0[12] = fmaf(w0, u3.x, acc0[12]); acc1[12] = fmaf(w1, u3.x, acc1[12]); \
        acc0[13] = fmaf(w0, u3.y, acc0[13]); acc1[13] = fmaf(w1, u3.y, acc1[13]); \
        acc0[14] = fmaf(w0, u3.z, acc0[14]); acc1[14] = fmaf(w1, u3.z, acc1[14]); \
        acc0[15] = fmaf(w0, u3.w, acc0[15]); acc1[15] = fmaf(w1, u3.w, acc1[15]); \
    }

    // ---- Software-pipelined main loop: prefetch jj+1 while computing jj ----
    float4 pA = *reinterpret_cast<const float4*>(&sj[0][0]);
    float2 pB = *reinterpret_cast<const float2*>(&sj[0][4]);
    float4 pu0 = *reinterpret_cast<const float4*>(&su[0][0]);
    float4 pu1 = *reinterpret_cast<const float4*>(&su[0][4]);
    float4 pu2 = *reinterpret_cast<const float4*>(&su[0][8]);
    float4 pu3 = *reinterpret_cast<const float4*>(&su[0][12]);

    for (int jj = 0; jj < JPB; jj += 2) {
        // prefetch odd row (jj+1)
        const float4 qA  = *reinterpret_cast<const float4*>(&sj[jj + 1][0]);
        const float2 qB  = *reinterpret_cast<const float2*>(&sj[jj + 1][4]);
        const float4 qu0 = *reinterpret_cast<const float4*>(&su[jj + 1][0]);
        const float4 qu1 = *reinterpret_cast<const float4*>(&su[jj + 1][4]);
        const float4 qu2 = *reinterpret_cast<const float4*>(&su[jj + 1][8]);
        const float4 qu3 = *reinterpret_cast<const float4*>(&su[jj + 1][12]);

        LG_COMPUTE(pA, pB, pu0, pu1, pu2, pu3);

        // prefetch next even row (jj+2; row JPB is the pad -> safe)
        pA  = *reinterpret_cast<const float4*>(&sj[jj + 2][0]);
        pB  = *reinterpret_cast<const float2*>(&sj[jj + 2][4]);
        pu0 = *reinterpret_cast<const float4*>(&su[jj + 2][0]);
        pu1 = *reinterpret_cast<const float4*>(&su[jj + 2][4]);
        pu2 = *reinterpret_cast<const float4*>(&su[jj + 2][8]);
        pu3 = *reinterpret_cast<const float4*>(&su[jj + 2][12]);

        LG_COMPUTE(qA, qB, qu0, qu1, qu2, qu3);
    }
#undef LG_COMPUTE

    // part layout: [seg][cq][i] as float4 -> coalesced stores (lanes = i).
    float4* part4 = reinterpret_cast<float4*>(part);
#pragma unroll
    for (int cq = 0; cq < 4; ++cq) {
        part4[((size_t)seg * 4 + cq) * N_ROWS + i0] =
            make_float4(acc0[cq * 4 + 0], acc0[cq * 4 + 1],
                        acc0[cq * 4 + 2], acc0[cq * 4 + 3]);
        part4[((size_t)seg * 4 + cq) * N_ROWS + i1] =
            make_float4(acc1[cq * 4 + 0], acc1[cq * 4 + 1],
                        acc1[cq * 4 + 2], acc1[cq * 4 + 3]);
    }
}

__global__ __launch_bounds__(TPB) void lg_reduce(const float* __restrict__ U,
                                                 const float* __restrict__ part,
                                                 float* __restrict__ out) {
    const int t  = blockIdx.x * TPB + threadIdx.x;  // [0, 32768)
    const int i  = t & (N_ROWS - 1);
    const int cq = t >> 13;                         // N_ROWS = 2^13
    const float4 u = reinterpret_cast<const float4*>(U)[i * 4 + cq];
    float4 s = make_float4(-u.x, -u.y, -u.z, -u.w);
    const float4* p = reinterpret_cast<const float4*>(part);
#pragma unroll 8
    for (int seg = 0; seg < NSEG; ++seg) {
        const float4 v = p[((size_t)seg * 4 + cq) * N_ROWS + i];
        s.x += v.x; s.y += v.y; s.z += v.z; s.w += v.w;
    }
    reinterpret_cast<float4*>(out)[i * 4 + cq] = s;
}

// ---- Last-resort fallback (ws too small): init -U + atomics ----

__global__ __launch_bounds__(TPB) void lg_init(const float* __restrict__ U,
                                               float* __restrict__ out) {
    const int idx = blockIdx.x * TPB + threadIdx.x;
    if (idx < N_ROWS * C_CH) out[idx] = -U[idx];
}

__global__ __launch_bounds__(TPB) void lg_main_atomic(const float* __restrict__ U,
                                                      const float* __restrict__ ref,
                                                      float* __restrict__ out) {
    constexpr int NS  = 32;
    constexpr int JP  = N_ROWS / NS;
    constexpr int NI  = N_ROWS / TPB;
    const int bid = blockIdx.x;
    const int ib  = bid % NI;
    const int sg  = bid / NI;
    const int i   = ib * TPB + threadIdx.x;

    const float r0 = ref[i * D_DIM + 0];
    const float r1 = ref[i * D_DIM + 1];
    const float r2 = ref[i * D_DIM + 2];
    const float r3 = ref[i * D_DIM + 3];
    const float r4 = ref[i * D_DIM + 4];

    float acc[C_CH];
#pragma unroll
    for (int c = 0; c < C_CH; ++c) acc[c] = 0.0f;

    const float4* __restrict__ U4 = reinterpret_cast<const float4*>(U);
    const int j0 = sg * JP;
#pragma unroll 4
    for (int j = j0; j < j0 + JP; ++j) {
        const float d0 = r0 - ref[j * D_DIM + 0];
        const float d1 = r1 - ref[j * D_DIM + 1];
        const float d2 = r2 - ref[j * D_DIM + 2];
        const float d3 = r3 - ref[j * D_DIM + 3];
        const float d4 = r4 - ref[j * D_DIM + 4];
        float dsq = d0 * d0;
        dsq = fmaf(d1, d1, dsq); dsq = fmaf(d2, d2, dsq);
        dsq = fmaf(d3, d3, dsq); dsq = fmaf(d4, d4, dsq);
        const float w = __expf(-0.5f * dsq);

        const float4 u0 = U4[j * 4 + 0];
        const float4 u1 = U4[j * 4 + 1];
        const float4 u2 = U4[j * 4 + 2];
        const float4 u3 = U4[j * 4 + 3];
        acc[0]  = fmaf(w, u0.x, acc[0]);   acc[1]  = fmaf(w, u0.y, acc[1]);
        acc[2]  = fmaf(w, u0.z, acc[2]);   acc[3]  = fmaf(w, u0.w, acc[3]);
        acc[4]  = fmaf(w, u1.x, acc[4]);   acc[5]  = fmaf(w, u1.y, acc[5]);
        acc[6]  = fmaf(w, u1.z, acc[6]);   acc[7]  = fmaf(w, u1.w, acc[7]);
        acc[8]  = fmaf(w, u2.x, acc[8]);   acc[9]  = fmaf(w, u2.y, acc[9]);
        acc[10] = fmaf(w, u2.z, acc[10]);  acc[11] = fmaf(w, u2.w, acc[11]);
        acc[12] = fmaf(w, u3.x, acc[12]);  acc[13] = fmaf(w, u3.y, acc[13]);
        acc[14] = fmaf(w, u3.z, acc[14]);  acc[15] = fmaf(w, u3.w, acc[15]);
    }

    float* o = out + (size_t)i * C_CH;
#pragma unroll
    for (int c = 0; c < C_CH; ++c) atomicAdd(&o[c], acc[c]);
}

extern "C" void kernel_launch(void* const* d_in, const int* in_sizes, int n_in,
                              void* d_out, int out_size, void* d_ws, size_t ws_size,
                              hipStream_t stream) {
    const float* U   = (const float*)d_in[0];   // [8192,16]
    const float* ref = (const float*)d_in[1];   // [8192,5]
    float* out       = (float*)d_out;           // [8192,16]

    const size_t need = (size_t)NSEG * N_ROWS * C_CH * sizeof(float);  // 33.6MB

    if (ws_size >= need) {
        float* part = (float*)d_ws;
        hipLaunchKernelGGL(lg_main, dim3(NIB * NSEG), dim3(TPB), 0, stream,
                           U, ref, part);
        hipLaunchKernelGGL(lg_reduce, dim3(N_ROWS * C_CH / 4 / TPB), dim3(TPB),
                           0, stream, U, part, out);
    } else {
        hipLaunchKernelGGL(lg_init, dim3((N_ROWS * C_CH + TPB - 1) / TPB), dim3(TPB),
                           0, stream, U, out);
        hipLaunchKernelGGL(lg_main_atomic, dim3((N_ROWS / TPB) * 32), dim3(TPB),
                           0, stream, U, ref, out);
    }
}